// Round 1
// baseline (9797.772 us; speedup 1.0000x reference)
//
#include <hip/hip_runtime.h>
#include <math.h>

#define OBS 8
#define SEQL 12
#define G 96
#define PP 16
#define B 1536
#define HD 128
#define ED 64
#define BOT 1024
#define MIDD 512
#define CTXD (HD + BOT)   /* 1152 */
#define MLPH 1024

// ---------------------------------------------------------------------------
// setup: transposes (so hot loops load weights coalesced) + M/cvec fold
// ---------------------------------------------------------------------------
__global__ void transpose_sub_kernel(const float* __restrict__ src, float* __restrict__ dst,
                                     int rows, int cols_total, int col_off, int cols_sub) {
    int idx = blockIdx.x * blockDim.x + threadIdx.x;
    int total = rows * cols_sub;
    if (idx >= total) return;
    int r = idx / cols_sub;
    int c = idx - r * cols_sub;
    dst[c * rows + r] = src[r * cols_total + col_off + c];
}

// M = Wp1[:, :64] @ Wp_emb  (512x2), cvec = Wp1[:, :64] @ bp_emb + bp1
__global__ void mcvec_kernel(const float* __restrict__ Wp1, const float* __restrict__ Wp_emb,
                             const float* __restrict__ bp_emb, const float* __restrict__ bp1,
                             float* __restrict__ M0, float* __restrict__ M1, float* __restrict__ CV) {
    int r = blockIdx.x * blockDim.x + threadIdx.x;
    if (r >= MIDD) return;
    float m0 = 0.f, m1 = 0.f, cv = 0.f;
    for (int e = 0; e < ED; ++e) {
        float w = Wp1[r * (ED + HD) + e];
        m0 += w * Wp_emb[e * 2 + 0];
        m1 += w * Wp_emb[e * 2 + 1];
        cv += w * bp_emb[e];
    }
    M0[r] = m0; M1[r] = m1; CV[r] = cv + bp1[r];
}

// init carry: H=h0, C=c0, POS=obs_traj[-1], DECIN = obs_traj_rel[-1] @ W_emb.T + b_emb
__global__ void init_kernel(const float* __restrict__ obs_traj, const float* __restrict__ obs_traj_rel,
                            const float* __restrict__ h0, const float* __restrict__ c0,
                            const float* __restrict__ W_emb, const float* __restrict__ b_emb,
                            float* __restrict__ Hb, float* __restrict__ Cb,
                            float* __restrict__ POSb, float* __restrict__ DIN) {
    int b = blockIdx.x;
    int t = threadIdx.x; // 128
    Hb[b * HD + t] = h0[b * HD + t];
    Cb[b * HD + t] = c0[b * HD + t];
    if (t < 2) POSb[b * 2 + t] = obs_traj[((OBS - 1) * B + b) * 2 + t];
    if (t < ED) {
        float rx = obs_traj_rel[((OBS - 1) * B + b) * 2 + 0];
        float ry = obs_traj_rel[((OBS - 1) * B + b) * 2 + 1];
        DIN[b * ED + t] = W_emb[t * 2 + 0] * rx + W_emb[t * 2 + 1] * ry + b_emb[t];
    }
}

// ---------------------------------------------------------------------------
// fused LSTM step + rel_pos + curr_pos + next dec_in + A = M@p + Wp1_h@h + cvec
// 512 threads = 4 rows per block (amortize weight L2 traffic)
// ---------------------------------------------------------------------------
__global__ __launch_bounds__(512) void lstm_kernel(
    const float* __restrict__ W_ihT, const float* __restrict__ b_ih,
    const float* __restrict__ W_hhT, const float* __restrict__ b_hh,
    const float* __restrict__ W_pos, const float* __restrict__ b_pos,
    const float* __restrict__ W_emb, const float* __restrict__ b_emb,
    const float* __restrict__ Wp1hT, const float* __restrict__ M0,
    const float* __restrict__ M1, const float* __restrict__ CV,
    float* __restrict__ Hb, float* __restrict__ Cb, float* __restrict__ POSb,
    float* __restrict__ DIN, float* __restrict__ Ab, float* __restrict__ rel_out) {

    __shared__ float din[4][ED];
    __shared__ float hprev[4][HD];
    __shared__ float hnew[4][HD];
    __shared__ float red0[4][HD];
    __shared__ float red1[4][HD];
    __shared__ float relsh[4][4];

    int t = threadIdx.x;
    int bsub = t >> 7;          // 0..3
    int ts = t & 127;           // 0..127
    int b = blockIdx.x * 4 + bsub;

    hprev[bsub][ts] = Hb[b * HD + ts];
    if (ts < ED) din[bsub][ts] = DIN[b * ED + ts];
    __syncthreads();

    float g[4];
#pragma unroll
    for (int x = 0; x < 4; ++x) {
        int r = x * HD + ts;
        float acc = b_ih[r] + b_hh[r];
        for (int k = 0; k < ED; ++k) acc = fmaf(W_ihT[k * (4 * HD) + r], din[bsub][k], acc);
        for (int k = 0; k < HD; ++k) acc = fmaf(W_hhT[k * (4 * HD) + r], hprev[bsub][k], acc);
        g[x] = acc;
    }
    float c = Cb[b * HD + ts];
    float ig = 1.f / (1.f + expf(-g[0]));
    float fg = 1.f / (1.f + expf(-g[1]));
    float gg = tanhf(g[2]);
    float og = 1.f / (1.f + expf(-g[3]));
    float cn = fg * c + ig * gg;
    float hn = og * tanhf(cn);
    Cb[b * HD + ts] = cn;
    Hb[b * HD + ts] = hn;
    hnew[bsub][ts] = hn;
    red0[bsub][ts] = hn * W_pos[ts];
    red1[bsub][ts] = hn * W_pos[HD + ts];
    __syncthreads();
    for (int s = 64; s > 0; s >>= 1) {
        if (ts < s) {
            red0[bsub][ts] += red0[bsub][ts + s];
            red1[bsub][ts] += red1[bsub][ts + s];
        }
        __syncthreads();
    }
    if (ts == 0) {
        float r0 = red0[bsub][0] + b_pos[0];
        float r1 = red1[bsub][0] + b_pos[1];
        float px = POSb[b * 2 + 0] + r0;
        float py = POSb[b * 2 + 1] + r1;
        POSb[b * 2 + 0] = px; POSb[b * 2 + 1] = py;
        rel_out[b * 2 + 0] = r0; rel_out[b * 2 + 1] = r1;
        relsh[bsub][0] = r0; relsh[bsub][1] = r1; relsh[bsub][2] = px; relsh[bsub][3] = py;
    }
    __syncthreads();
    float r0 = relsh[bsub][0], r1 = relsh[bsub][1];
    float px = relsh[bsub][2], py = relsh[bsub][3];
    if (ts < ED)
        DIN[b * ED + ts] = W_emb[ts * 2 + 0] * r0 + W_emb[ts * 2 + 1] * r1 + b_emb[ts];
#pragma unroll
    for (int q = 0; q < 4; ++q) {
        int r = ts + HD * q;   // 0..511
        float acc = CV[r] + M0[r] * px + M1[r] * py;
        for (int k = 0; k < HD; ++k) acc = fmaf(Wp1hT[k * MIDD + r], hnew[bsub][k], acc);
        Ab[b * MIDD + r] = acc;
    }
}

// ---------------------------------------------------------------------------
// pool: block per (scene g, ped i). Y1[j][k] = relu(a_j[k] - s_i[k]) in LDS,
// then out[r] = relu(max_j sum_k Wp2[r,k]*Y1[j][k] + bp2[r])
// ---------------------------------------------------------------------------
__global__ __launch_bounds__(256) void pool_kernel(
    const float* __restrict__ Ab, const float* __restrict__ POSb,
    const float* __restrict__ Wp2T, const float* __restrict__ bp2,
    const float* __restrict__ M0, const float* __restrict__ M1,
    float* __restrict__ POOL) {

    __shared__ float sM[MIDD];
    __shared__ __align__(16) float Y1[PP * MIDD];   // 16x512 = 32KB

    int bi = blockIdx.x;   // g*16 + i
    int g = bi >> 4;
    int t = threadIdx.x;

    float px = POSb[bi * 2 + 0], py = POSb[bi * 2 + 1];
    sM[t] = M0[t] * px + M1[t] * py;
    sM[t + 256] = M0[t + 256] * px + M1[t + 256] * py;
    __syncthreads();

    const float* Ag = Ab + g * (PP * MIDD);
#pragma unroll
    for (int it = 0; it < 32; ++it) {
        int idx = t + 256 * it;
        int k = idx & (MIDD - 1);
        float v = Ag[idx] - sM[k];
        Y1[idx] = v > 0.f ? v : 0.f;
    }
    __syncthreads();

    float acc[4][PP];
#pragma unroll
    for (int q = 0; q < 4; ++q)
#pragma unroll
        for (int j = 0; j < PP; ++j) acc[q][j] = 0.f;

    const float* wp = Wp2T + t;
    for (int kk = 0; kk < MIDD; kk += 4) {
        float w[4][4];
#pragma unroll
        for (int kx = 0; kx < 4; ++kx)
#pragma unroll
            for (int q = 0; q < 4; ++q)
                w[kx][q] = wp[(kk + kx) * BOT + 256 * q];
#pragma unroll
        for (int j = 0; j < PP; ++j) {
            const float4 y = *(const float4*)&Y1[j * MIDD + kk];
#pragma unroll
            for (int q = 0; q < 4; ++q) {
                acc[q][j] = fmaf(w[0][q], y.x, acc[q][j]);
                acc[q][j] = fmaf(w[1][q], y.y, acc[q][j]);
                acc[q][j] = fmaf(w[2][q], y.z, acc[q][j]);
                acc[q][j] = fmaf(w[3][q], y.w, acc[q][j]);
            }
        }
    }
#pragma unroll
    for (int q = 0; q < 4; ++q) {
        int r = t + 256 * q;
        float m = acc[q][0];
#pragma unroll
        for (int j = 1; j < PP; ++j) m = fmaxf(m, acc[q][j]);
        m += bp2[r];
        m = m > 0.f ? m : 0.f;
        POOL[bi * BOT + r] = m;
    }
}

// ---------------------------------------------------------------------------
// MLP layer1: Y1M = relu([H|POOL] @ Wm1.T + bm1). Tile: 16 rows x 256 cols.
// ---------------------------------------------------------------------------
__global__ __launch_bounds__(256) void mlp1_kernel(
    const float* __restrict__ Hb, const float* __restrict__ POOL,
    const float* __restrict__ Wm1T, const float* __restrict__ bm1,
    float* __restrict__ Y1M) {

    __shared__ float ctx[16 * 64];
    int bg = blockIdx.x;   // 0..95
    int rc = blockIdx.y;   // 0..3
    int t = threadIdx.x;
    int r = rc * 256 + t;

    float acc[16];
#pragma unroll
    for (int b = 0; b < 16; ++b) acc[b] = 0.f;

    for (int kc = 0; kc < CTXD / 64; ++kc) {   // 18 chunks
        __syncthreads();
#pragma unroll
        for (int it = 0; it < 4; ++it) {
            int idx = t + 256 * it;      // 0..1023
            int bb = idx >> 6;
            int k = idx & 63;
            int kg = kc * 64 + k;
            int row = bg * 16 + bb;
            float v = (kg < HD) ? Hb[row * HD + kg] : POOL[row * BOT + (kg - HD)];
            ctx[idx] = v;
        }
        __syncthreads();
        for (int k = 0; k < 64; ++k) {
            float w = Wm1T[(kc * 64 + k) * MLPH + r];
#pragma unroll
            for (int b = 0; b < 16; ++b) acc[b] = fmaf(w, ctx[b * 64 + k], acc[b]);
        }
    }
#pragma unroll
    for (int b = 0; b < 16; ++b) {
        float v = acc[b] + bm1[r];
        Y1M[(bg * 16 + b) * MLPH + r] = v > 0.f ? v : 0.f;
    }
}

// ---------------------------------------------------------------------------
// MLP layer2: h = relu(Y1M @ Wm2.T + bm2) -> Hb (and final output on last step)
// ---------------------------------------------------------------------------
__global__ __launch_bounds__(128) void mlp2_kernel(
    const float* __restrict__ Y1M, const float* __restrict__ Wm2T,
    const float* __restrict__ bm2, float* __restrict__ Hb,
    float* __restrict__ hout) {

    __shared__ float ych[4 * 128];
    int bg = blockIdx.x;   // 0..383
    int t = threadIdx.x;   // 128

    float acc[4] = {0.f, 0.f, 0.f, 0.f};
    for (int kc = 0; kc < MLPH / 128; ++kc) {   // 8
        __syncthreads();
#pragma unroll
        for (int b = 0; b < 4; ++b) ych[b * 128 + t] = Y1M[(bg * 4 + b) * MLPH + kc * 128 + t];
        __syncthreads();
        for (int k = 0; k < 128; ++k) {
            float w = Wm2T[(kc * 128 + k) * HD + t];
#pragma unroll
            for (int b = 0; b < 4; ++b) acc[b] = fmaf(w, ych[b * 128 + k], acc[b]);
        }
    }
#pragma unroll
    for (int b = 0; b < 4; ++b) {
        float v = acc[b] + bm2[t];
        v = v > 0.f ? v : 0.f;
        Hb[(bg * 4 + b) * HD + t] = v;
        if (hout) hout[(bg * 4 + b) * HD + t] = v;
    }
}

// ---------------------------------------------------------------------------
extern "C" void kernel_launch(void* const* d_in, const int* in_sizes, int n_in,
                              void* d_out, int out_size, void* d_ws, size_t ws_size,
                              hipStream_t stream) {
    const float* obs_traj     = (const float*)d_in[0];
    const float* obs_traj_rel = (const float*)d_in[1];
    const float* h0    = (const float*)d_in[3];
    const float* c0    = (const float*)d_in[4];
    const float* W_emb = (const float*)d_in[6];
    const float* b_emb = (const float*)d_in[7];
    const float* W_ih  = (const float*)d_in[8];
    const float* b_ih  = (const float*)d_in[9];
    const float* W_hh  = (const float*)d_in[10];
    const float* b_hh  = (const float*)d_in[11];
    const float* W_pos = (const float*)d_in[12];
    const float* b_pos = (const float*)d_in[13];
    const float* Wp_emb= (const float*)d_in[14];
    const float* bp_emb= (const float*)d_in[15];
    const float* Wp1   = (const float*)d_in[16];
    const float* bp1   = (const float*)d_in[17];
    const float* Wp2   = (const float*)d_in[18];
    const float* bp2   = (const float*)d_in[19];
    const float* Wm1   = (const float*)d_in[20];
    const float* bm1   = (const float*)d_in[21];
    const float* Wm2   = (const float*)d_in[22];
    const float* bm2   = (const float*)d_in[23];

    float* ws = (float*)d_ws;
    float* Hb    = ws; ws += B * HD;              // 196608
    float* Cb    = ws; ws += B * HD;              // 196608
    float* POSb  = ws; ws += B * 2;               // 3072
    float* DIN   = ws; ws += B * ED;              // 98304
    float* Ab    = ws; ws += B * MIDD;            // 786432
    float* POOL  = ws; ws += B * BOT;             // 1572864
    float* Y1M   = ws; ws += B * MLPH;            // 1572864
    float* W_ihT = ws; ws += ED * 4 * HD;         // 32768
    float* W_hhT = ws; ws += HD * 4 * HD;         // 65536
    float* Wp1hT = ws; ws += HD * MIDD;           // 65536
    float* Wp2T  = ws; ws += MIDD * BOT;          // 524288
    float* Wm1T  = ws; ws += CTXD * MLPH;         // 1179648
    float* Wm2T  = ws; ws += MLPH * HD;           // 131072
    float* M0    = ws; ws += MIDD;
    float* M1    = ws; ws += MIDD;
    float* CV    = ws; ws += MIDD;

    float* out = (float*)d_out;
    float* rels_out = out;                        // (12,1536,2)
    float* h_out    = out + SEQL * B * 2;         // (1536,128)

    // setup: weight transposes + folded M/cvec
    auto tl = [&](const float* src, float* dst, int rows, int ct, int off, int cs) {
        int total = rows * cs;
        transpose_sub_kernel<<<(total + 255) / 256, 256, 0, stream>>>(src, dst, rows, ct, off, cs);
    };
    tl(W_ih, W_ihT, 4 * HD, ED, 0, ED);
    tl(W_hh, W_hhT, 4 * HD, HD, 0, HD);
    tl(Wp1, Wp1hT, MIDD, ED + HD, ED, HD);
    tl(Wp2, Wp2T, BOT, MIDD, 0, MIDD);
    tl(Wm1, Wm1T, MLPH, CTXD, 0, CTXD);
    tl(Wm2, Wm2T, HD, MLPH, 0, MLPH);
    mcvec_kernel<<<2, 256, 0, stream>>>(Wp1, Wp_emb, bp_emb, bp1, M0, M1, CV);
    init_kernel<<<B, 128, 0, stream>>>(obs_traj, obs_traj_rel, h0, c0, W_emb, b_emb,
                                       Hb, Cb, POSb, DIN);

    for (int s = 0; s < SEQL; ++s) {
        lstm_kernel<<<B / 4, 512, 0, stream>>>(
            W_ihT, b_ih, W_hhT, b_hh, W_pos, b_pos, W_emb, b_emb,
            Wp1hT, M0, M1, CV, Hb, Cb, POSb, DIN, Ab, rels_out + s * B * 2);
        pool_kernel<<<B, 256, 0, stream>>>(Ab, POSb, Wp2T, bp2, M0, M1, POOL);
        mlp1_kernel<<<dim3(G, 4), 256, 0, stream>>>(Hb, POOL, Wm1T, bm1, Y1M);
        mlp2_kernel<<<B / 4, 128, 0, stream>>>(Y1M, Wm2T, bm2, Hb,
                                               (s == SEQL - 1) ? h_out : (float*)nullptr);
    }
}

// Round 2
// 1399.067 us; speedup vs baseline: 7.0031x; 7.0031x over previous
//
#include <hip/hip_runtime.h>
#include <math.h>

#define OBS 8
#define SEQL 12
#define G 96
#define PP 16
#define B 1536
#define HD 128
#define ED 64
#define BOT 1024
#define MIDD 512
#define CTXD (HD + BOT)   /* 1152 */
#define MLPH 1024

typedef __attribute__((ext_vector_type(8))) short bf16x8;
typedef __attribute__((ext_vector_type(4))) float f32x4;

__device__ inline short f2bf(float x) {
    union { float f; unsigned u; } v; v.f = x;
    unsigned r = v.u + 0x7fffu + ((v.u >> 16) & 1u);   // RNE
    return (short)(r >> 16);
}

// ---------------------------------------------------------------------------
// setup kernels
// ---------------------------------------------------------------------------
__global__ void transpose_sub_kernel(const float* __restrict__ src, float* __restrict__ dst,
                                     int rows, int cols_total, int col_off, int cols_sub) {
    int idx = blockIdx.x * blockDim.x + threadIdx.x;
    int total = rows * cols_sub;
    if (idx >= total) return;
    int r = idx / cols_sub;
    int c = idx - r * cols_sub;
    dst[c * rows + r] = src[r * cols_total + col_off + c];
}

// B-matrix -> MFMA-fragment-order bf16. src is (Nrows x Kcols) row-major fp32.
// dst unit u = (kt*NT + nt)*64 + lane, holding 8 bf16: B[n=nt*16+(l&15)][k=kt*32+((l>>4)<<3)+e]
__global__ void swizzleB_kernel(const float* __restrict__ src, unsigned short* __restrict__ dst,
                                int NT, int K, int total) {
    int u = blockIdx.x * 256 + threadIdx.x;
    if (u >= total) return;
    int l = u & 63; int v = u >> 6; int nt = v % NT; int kt = v / NT;
    int n = nt * 16 + (l & 15);
    int k = kt * 32 + ((l >> 4) << 3);
    const float* s = src + n * K + k;
    float4 s0 = *(const float4*)s;
    float4 s1 = *(const float4*)(s + 4);
    bf16x8 o;
    o[0] = f2bf(s0.x); o[1] = f2bf(s0.y); o[2] = f2bf(s0.z); o[3] = f2bf(s0.w);
    o[4] = f2bf(s1.x); o[5] = f2bf(s1.y); o[6] = f2bf(s1.z); o[7] = f2bf(s1.w);
    *(bf16x8*)(dst + u * 8) = o;
}

// M = Wp1[:, :64] @ Wp_emb  (512x2), cvec = Wp1[:, :64] @ bp_emb + bp1
__global__ void mcvec_kernel(const float* __restrict__ Wp1, const float* __restrict__ Wp_emb,
                             const float* __restrict__ bp_emb, const float* __restrict__ bp1,
                             float* __restrict__ M0, float* __restrict__ M1, float* __restrict__ CV) {
    int r = blockIdx.x * blockDim.x + threadIdx.x;
    if (r >= MIDD) return;
    float m0 = 0.f, m1 = 0.f, cv = 0.f;
    for (int e = 0; e < ED; ++e) {
        float w = Wp1[r * (ED + HD) + e];
        m0 += w * Wp_emb[e * 2 + 0];
        m1 += w * Wp_emb[e * 2 + 1];
        cv += w * bp_emb[e];
    }
    M0[r] = m0; M1[r] = m1; CV[r] = cv + bp1[r];
}

__global__ void init_kernel(const float* __restrict__ obs_traj, const float* __restrict__ obs_traj_rel,
                            const float* __restrict__ h0, const float* __restrict__ c0,
                            const float* __restrict__ W_emb, const float* __restrict__ b_emb,
                            float* __restrict__ Hb, float* __restrict__ Cb,
                            float* __restrict__ POSb, float* __restrict__ DIN) {
    int b = blockIdx.x;
    int t = threadIdx.x; // 128
    Hb[b * HD + t] = h0[b * HD + t];
    Cb[b * HD + t] = c0[b * HD + t];
    if (t < 2) POSb[b * 2 + t] = obs_traj[((OBS - 1) * B + b) * 2 + t];
    if (t < ED) {
        float rx = obs_traj_rel[((OBS - 1) * B + b) * 2 + 0];
        float ry = obs_traj_rel[((OBS - 1) * B + b) * 2 + 1];
        DIN[b * ED + t] = W_emb[t * 2 + 0] * rx + W_emb[t * 2 + 1] * ry + b_emb[t];
    }
}

// ---------------------------------------------------------------------------
// fused LSTM step + rel_pos + curr_pos + next dec_in + A = M@p + Wp1_h@h + cvec
// (fp32 throughout; also emits bf16 copy of h for the MFMA MLP1)
// ---------------------------------------------------------------------------
__global__ __launch_bounds__(512) void lstm_kernel(
    const float* __restrict__ W_ihT, const float* __restrict__ b_ih,
    const float* __restrict__ W_hhT, const float* __restrict__ b_hh,
    const float* __restrict__ W_pos, const float* __restrict__ b_pos,
    const float* __restrict__ W_emb, const float* __restrict__ b_emb,
    const float* __restrict__ Wp1hT, const float* __restrict__ M0,
    const float* __restrict__ M1, const float* __restrict__ CV,
    float* __restrict__ Hb, float* __restrict__ Cb, float* __restrict__ POSb,
    float* __restrict__ DIN, float* __restrict__ Ab, float* __restrict__ rel_out,
    unsigned short* __restrict__ Hbf) {

    __shared__ float din[4][ED];
    __shared__ float hprev[4][HD];
    __shared__ float hnew[4][HD];
    __shared__ float red0[4][HD];
    __shared__ float red1[4][HD];
    __shared__ float relsh[4][4];

    int t = threadIdx.x;
    int bsub = t >> 7;          // 0..3
    int ts = t & 127;           // 0..127
    int b = blockIdx.x * 4 + bsub;

    hprev[bsub][ts] = Hb[b * HD + ts];
    if (ts < ED) din[bsub][ts] = DIN[b * ED + ts];
    __syncthreads();

    float g[4];
#pragma unroll
    for (int x = 0; x < 4; ++x) {
        int r = x * HD + ts;
        float acc = b_ih[r] + b_hh[r];
        for (int k = 0; k < ED; ++k) acc = fmaf(W_ihT[k * (4 * HD) + r], din[bsub][k], acc);
        for (int k = 0; k < HD; ++k) acc = fmaf(W_hhT[k * (4 * HD) + r], hprev[bsub][k], acc);
        g[x] = acc;
    }
    float c = Cb[b * HD + ts];
    float ig = 1.f / (1.f + expf(-g[0]));
    float fg = 1.f / (1.f + expf(-g[1]));
    float gg = tanhf(g[2]);
    float og = 1.f / (1.f + expf(-g[3]));
    float cn = fg * c + ig * gg;
    float hn = og * tanhf(cn);
    Cb[b * HD + ts] = cn;
    Hb[b * HD + ts] = hn;
    Hbf[b * HD + ts] = (unsigned short)f2bf(hn);
    hnew[bsub][ts] = hn;
    red0[bsub][ts] = hn * W_pos[ts];
    red1[bsub][ts] = hn * W_pos[HD + ts];
    __syncthreads();
    for (int s = 64; s > 0; s >>= 1) {
        if (ts < s) {
            red0[bsub][ts] += red0[bsub][ts + s];
            red1[bsub][ts] += red1[bsub][ts + s];
        }
        __syncthreads();
    }
    if (ts == 0) {
        float r0 = red0[bsub][0] + b_pos[0];
        float r1 = red1[bsub][0] + b_pos[1];
        float px = POSb[b * 2 + 0] + r0;
        float py = POSb[b * 2 + 1] + r1;
        POSb[b * 2 + 0] = px; POSb[b * 2 + 1] = py;
        rel_out[b * 2 + 0] = r0; rel_out[b * 2 + 1] = r1;
        relsh[bsub][0] = r0; relsh[bsub][1] = r1; relsh[bsub][2] = px; relsh[bsub][3] = py;
    }
    __syncthreads();
    float r0 = relsh[bsub][0], r1 = relsh[bsub][1];
    float px = relsh[bsub][2], py = relsh[bsub][3];
    if (ts < ED)
        DIN[b * ED + ts] = W_emb[ts * 2 + 0] * r0 + W_emb[ts * 2 + 1] * r1 + b_emb[ts];
#pragma unroll
    for (int q = 0; q < 4; ++q) {
        int r = ts + HD * q;   // 0..511
        float acc = CV[r] + M0[r] * px + M1[r] * py;
        for (int k = 0; k < HD; ++k) acc = fmaf(Wp1hT[k * MIDD + r], hnew[bsub][k], acc);
        Ab[b * MIDD + r] = acc;
    }
}

// ---------------------------------------------------------------------------
// pool (MFMA): grid = (g,nc) 96x8, 512 thr (8 waves). Per block: scene g,
// cols nc*128..+127. Wave w: i-group (w>>1)*4..+3, col-half (w&1)*64.
// A_i[j][k] = relu(a_j[k] - s_i[k]) built per k-step from LDS; B from Wp2F.
// C-tile rows = j -> max over rows via regs + 2x shfl_xor.
// ---------------------------------------------------------------------------
__global__ __launch_bounds__(512, 4) void pool_mfma_kernel(
    const float* __restrict__ Ab, const float* __restrict__ POSb,
    const unsigned short* __restrict__ Wp2F, const float* __restrict__ bp2,
    const float* __restrict__ M0, const float* __restrict__ M1,
    unsigned short* __restrict__ POOLbf) {

    __shared__ float a_f[16 * 128 * 4];   // [kt][h*64+l] float4 units, 32KB
    __shared__ float s_lds[PP * MIDD];    // 32KB

    int g = blockIdx.x >> 3;
    int nc = blockIdx.x & 7;
    int t = threadIdx.x;
    int lane = t & 63;
    int w = t >> 6;
    int igrp = w >> 1;
    int nh = w & 1;
    int n_base = nc * 128 + nh * 64;

    // stage a (fragment order, fp32)
    const float* Ag = Ab + g * (PP * MIDD);
    {
        float4* a4 = (float4*)a_f;
        for (int u = t; u < 1024; u += 512) {
            int kt = u >> 6, l = u & 63;
            int j = l & 15, k = kt * 32 + ((l >> 4) << 3);
            const float4* src = (const float4*)(Ag + j * MIDD + k);
            a4[kt * 128 + l] = src[0];
            a4[kt * 128 + 64 + l] = src[1];
        }
    }
    // stage s[i][k] = M0[k]*px_i + M1[k]*py_i
    {
        int i = t >> 5;            // 0..15
        int kb = (t & 31) * 16;
        float px = POSb[(g * PP + i) * 2 + 0];
        float py = POSb[(g * PP + i) * 2 + 1];
        for (int k = kb; k < kb + 16; ++k)
            s_lds[i * MIDD + k] = fmaf(M0[k], px, M1[k] * py);
    }
    __syncthreads();

    f32x4 acc[4][4];
#pragma unroll
    for (int a = 0; a < 4; ++a)
#pragma unroll
        for (int bq = 0; bq < 4; ++bq) acc[a][bq] = (f32x4)0.f;

    const float4* a4 = (const float4*)a_f;
    int ntb = n_base >> 4;
    for (int kt = 0; kt < 16; ++kt) {
        bf16x8 bfr[4];
#pragma unroll
        for (int nt = 0; nt < 4; ++nt)
            bfr[nt] = *(const bf16x8*)(Wp2F + (((kt * 64) + ntb + nt) * 64 + lane) * 8);
        float4 av0 = a4[kt * 128 + lane];
        float4 av1 = a4[kt * 128 + 64 + lane];
        int soff = kt * 32 + ((lane >> 4) << 3);
#pragma unroll
        for (int ii = 0; ii < 4; ++ii) {
            int i = igrp * 4 + ii;
            const float4* sp = (const float4*)(s_lds + i * MIDD + soff);
            float4 s0 = sp[0], s1 = sp[1];
            bf16x8 af;
            af[0] = f2bf(fmaxf(av0.x - s0.x, 0.f));
            af[1] = f2bf(fmaxf(av0.y - s0.y, 0.f));
            af[2] = f2bf(fmaxf(av0.z - s0.z, 0.f));
            af[3] = f2bf(fmaxf(av0.w - s0.w, 0.f));
            af[4] = f2bf(fmaxf(av1.x - s1.x, 0.f));
            af[5] = f2bf(fmaxf(av1.y - s1.y, 0.f));
            af[6] = f2bf(fmaxf(av1.z - s1.z, 0.f));
            af[7] = f2bf(fmaxf(av1.w - s1.w, 0.f));
#pragma unroll
            for (int nt = 0; nt < 4; ++nt)
                acc[ii][nt] = __builtin_amdgcn_mfma_f32_16x16x32_bf16(af, bfr[nt], acc[ii][nt], 0, 0, 0);
        }
    }

    int quad = lane >> 4;
    int colid = lane & 15;
#pragma unroll
    for (int ii = 0; ii < 4; ++ii) {
        int i = igrp * 4 + ii;
#pragma unroll
        for (int nt = 0; nt < 4; ++nt) {
            float m = fmaxf(fmaxf(acc[ii][nt][0], acc[ii][nt][1]),
                            fmaxf(acc[ii][nt][2], acc[ii][nt][3]));
            m = fmaxf(m, __shfl_xor(m, 16, 64));
            m = fmaxf(m, __shfl_xor(m, 32, 64));
            if (quad == 0) {
                int n = n_base + nt * 16 + colid;
                float v = fmaxf(m + bp2[n], 0.f);
                POOLbf[(g * PP + i) * BOT + n] = (unsigned short)f2bf(v);
            }
        }
    }
}

// ---------------------------------------------------------------------------
// MLP1 (MFMA): [Hbf | POOLbf] (1536x1152) @ Wm1F -> relu -> Y1Mbf (1536x1024)
// grid (24,16): 64 rows x 64 cols per block, 256 thr (4 waves).
// ---------------------------------------------------------------------------
__global__ __launch_bounds__(256) void mlp1_mfma_kernel(
    const unsigned short* __restrict__ Hbf, const unsigned short* __restrict__ POOLbf,
    const unsigned short* __restrict__ Wm1F, const float* __restrict__ bm1,
    unsigned short* __restrict__ Y1Mbf) {

    __shared__ unsigned short a_f[16 * 64 * 8];   // 16KB: [rg*4+kt][l][8]
    int mg = blockIdx.x;       // 0..23
    int ng = blockIdx.y;       // 0..15
    int t = threadIdx.x, lane = t & 63, w = t >> 6;
    int rh = w >> 1, nh = w & 1;

    f32x4 acc[2][2];
#pragma unroll
    for (int a = 0; a < 2; ++a)
#pragma unroll
        for (int b = 0; b < 2; ++b) acc[a][b] = (f32x4)0.f;

    for (int c = 0; c < 9; ++c) {
        __syncthreads();
#pragma unroll
        for (int u0 = 0; u0 < 1024; u0 += 256) {
            int u = u0 + t;
            int rg = u >> 8, kt = (u >> 6) & 3, l = u & 63;
            int row = mg * 64 + rg * 16 + (l & 15);
            int kl = kt * 32 + ((l >> 4) << 3);
            const unsigned short* src = (c == 0) ? (Hbf + row * HD + kl)
                                                 : (POOLbf + row * BOT + (c - 1) * 128 + kl);
            *(bf16x8*)(a_f + u * 8) = *(const bf16x8*)src;
        }
        __syncthreads();
#pragma unroll
        for (int kt = 0; kt < 4; ++kt) {
            int ktg = c * 4 + kt;
            bf16x8 bfr[2];
#pragma unroll
            for (int j = 0; j < 2; ++j) {
                int ntg = ng * 4 + nh * 2 + j;
                bfr[j] = *(const bf16x8*)(Wm1F + ((ktg * 64 + ntg) * 64 + lane) * 8);
            }
#pragma unroll
            for (int ri = 0; ri < 2; ++ri) {
                int rg = rh * 2 + ri;
                bf16x8 af = *(const bf16x8*)(a_f + ((rg * 4 + kt) * 64 + lane) * 8);
#pragma unroll
                for (int j = 0; j < 2; ++j)
                    acc[ri][j] = __builtin_amdgcn_mfma_f32_16x16x32_bf16(af, bfr[j], acc[ri][j], 0, 0, 0);
            }
        }
    }
    int quad = lane >> 4, colid = lane & 15;
#pragma unroll
    for (int ri = 0; ri < 2; ++ri)
#pragma unroll
        for (int j = 0; j < 2; ++j) {
            int col = ng * 64 + (nh * 2 + j) * 16 + colid;
            float bb = bm1[col];
#pragma unroll
            for (int r = 0; r < 4; ++r) {
                int row = mg * 64 + (rh * 2 + ri) * 16 + quad * 4 + r;
                float v = fmaxf(acc[ri][j][r] + bb, 0.f);
                Y1Mbf[row * MLPH + col] = (unsigned short)f2bf(v);
            }
        }
}

// ---------------------------------------------------------------------------
// MLP2 (MFMA): Y1Mbf (1536x1024) @ Wm2F -> relu -> Hb fp32 (and h_out last step)
// grid 96 (16-row blocks), 256 thr (4 waves), each wave 2 n-tiles (32 cols).
// ---------------------------------------------------------------------------
__global__ __launch_bounds__(256) void mlp2_mfma_kernel(
    const unsigned short* __restrict__ Y1Mbf, const unsigned short* __restrict__ Wm2F,
    const float* __restrict__ bm2, float* __restrict__ Hb, float* __restrict__ hout) {

    __shared__ unsigned short a_f[32 * 64 * 8];   // 32KB
    int rg = blockIdx.x;   // 0..95
    int t = threadIdx.x, lane = t & 63, w = t >> 6;

#pragma unroll
    for (int u0 = 0; u0 < 2048; u0 += 256) {
        int u = u0 + t;
        int kt = u >> 6, l = u & 63;
        int row = rg * 16 + (l & 15);
        int kl = kt * 32 + ((l >> 4) << 3);
        *(bf16x8*)(a_f + u * 8) = *(const bf16x8*)(Y1Mbf + row * MLPH + kl);
    }
    __syncthreads();

    f32x4 acc[2];
    acc[0] = (f32x4)0.f; acc[1] = (f32x4)0.f;
    for (int kt = 0; kt < 32; ++kt) {
        bf16x8 af = *(const bf16x8*)(a_f + (kt * 64 + lane) * 8);
#pragma unroll
        for (int j = 0; j < 2; ++j) {
            int ntg = w * 2 + j;
            bf16x8 bfr = *(const bf16x8*)(Wm2F + ((kt * 8 + ntg) * 64 + lane) * 8);
            acc[j] = __builtin_amdgcn_mfma_f32_16x16x32_bf16(af, bfr, acc[j], 0, 0, 0);
        }
    }
    int quad = lane >> 4, colid = lane & 15;
#pragma unroll
    for (int j = 0; j < 2; ++j) {
        int col = (w * 2 + j) * 16 + colid;
        float bb = bm2[col];
#pragma unroll
        for (int r = 0; r < 4; ++r) {
            int row = rg * 16 + quad * 4 + r;
            float v = fmaxf(acc[j][r] + bb, 0.f);
            Hb[row * HD + col] = v;
            if (hout) hout[row * HD + col] = v;
        }
    }
}

// ---------------------------------------------------------------------------
extern "C" void kernel_launch(void* const* d_in, const int* in_sizes, int n_in,
                              void* d_out, int out_size, void* d_ws, size_t ws_size,
                              hipStream_t stream) {
    const float* obs_traj     = (const float*)d_in[0];
    const float* obs_traj_rel = (const float*)d_in[1];
    const float* h0    = (const float*)d_in[3];
    const float* c0    = (const float*)d_in[4];
    const float* W_emb = (const float*)d_in[6];
    const float* b_emb = (const float*)d_in[7];
    const float* W_ih  = (const float*)d_in[8];
    const float* b_ih  = (const float*)d_in[9];
    const float* W_hh  = (const float*)d_in[10];
    const float* b_hh  = (const float*)d_in[11];
    const float* W_pos = (const float*)d_in[12];
    const float* b_pos = (const float*)d_in[13];
    const float* Wp_emb= (const float*)d_in[14];
    const float* bp_emb= (const float*)d_in[15];
    const float* Wp1   = (const float*)d_in[16];
    const float* bp1   = (const float*)d_in[17];
    const float* Wp2   = (const float*)d_in[18];
    const float* bp2   = (const float*)d_in[19];
    const float* Wm1   = (const float*)d_in[20];
    const float* bm1   = (const float*)d_in[21];
    const float* Wm2   = (const float*)d_in[22];
    const float* bm2   = (const float*)d_in[23];

    float* ws = (float*)d_ws;
    float* Hb    = ws; ws += B * HD;
    float* Cb    = ws; ws += B * HD;
    float* POSb  = ws; ws += B * 2;
    float* DIN   = ws; ws += B * ED;
    float* Ab    = ws; ws += B * MIDD;
    float* W_ihT = ws; ws += ED * 4 * HD;
    float* W_hhT = ws; ws += HD * 4 * HD;
    float* Wp1hT = ws; ws += HD * MIDD;
    float* M0    = ws; ws += MIDD;
    float* M1    = ws; ws += MIDD;
    float* CV    = ws; ws += MIDD;
    unsigned short* us = (unsigned short*)ws;
    unsigned short* Hbf    = us; us += B * HD;
    unsigned short* POOLbf = us; us += B * BOT;
    unsigned short* Y1Mbf  = us; us += B * MLPH;
    unsigned short* Wp2F   = us; us += MIDD * BOT;
    unsigned short* Wm1F   = us; us += CTXD * MLPH;
    unsigned short* Wm2F   = us; us += MLPH * HD;

    float* out = (float*)d_out;
    float* rels_out = out;                 // (12,1536,2)
    float* h_out    = out + SEQL * B * 2;  // (1536,128)

    // setup
    auto tl = [&](const float* src, float* dst, int rows, int ct, int off, int cs) {
        int total = rows * cs;
        transpose_sub_kernel<<<(total + 255) / 256, 256, 0, stream>>>(src, dst, rows, ct, off, cs);
    };
    tl(W_ih, W_ihT, 4 * HD, ED, 0, ED);
    tl(W_hh, W_hhT, 4 * HD, HD, 0, HD);
    tl(Wp1, Wp1hT, MIDD, ED + HD, ED, HD);
    {   // fragment-order bf16 weights
        int tot = 16 * 64 * 64;   // Wp2: K=512 (KT=16), N=1024 (NT=64)
        swizzleB_kernel<<<(tot + 255) / 256, 256, 0, stream>>>(Wp2, Wp2F, 64, MIDD, tot);
        tot = 36 * 64 * 64;       // Wm1: K=1152 (KT=36), N=1024
        swizzleB_kernel<<<(tot + 255) / 256, 256, 0, stream>>>(Wm1, Wm1F, 64, CTXD, tot);
        tot = 32 * 8 * 64;        // Wm2: K=1024 (KT=32), N=128 (NT=8)
        swizzleB_kernel<<<(tot + 255) / 256, 256, 0, stream>>>(Wm2, Wm2F, 8, MLPH, tot);
    }
    mcvec_kernel<<<2, 256, 0, stream>>>(Wp1, Wp_emb, bp_emb, bp1, M0, M1, CV);
    init_kernel<<<B, 128, 0, stream>>>(obs_traj, obs_traj_rel, h0, c0, W_emb, b_emb,
                                       Hb, Cb, POSb, DIN);

    for (int s = 0; s < SEQL; ++s) {
        lstm_kernel<<<B / 4, 512, 0, stream>>>(
            W_ihT, b_ih, W_hhT, b_hh, W_pos, b_pos, W_emb, b_emb,
            Wp1hT, M0, M1, CV, Hb, Cb, POSb, DIN, Ab, rels_out + s * B * 2, Hbf);
        pool_mfma_kernel<<<G * 8, 512, 0, stream>>>(Ab, POSb, Wp2F, bp2, M0, M1, POOLbf);
        mlp1_mfma_kernel<<<dim3(24, 16), 256, 0, stream>>>(Hbf, POOLbf, Wm1F, bm1, Y1Mbf);
        mlp2_mfma_kernel<<<G, 256, 0, stream>>>(Y1Mbf, Wm2F, bm2, Hb,
                                                (s == SEQL - 1) ? h_out : (float*)nullptr);
    }
}

// Round 3
// 1098.610 us; speedup vs baseline: 8.9183x; 1.2735x over previous
//
#include <hip/hip_runtime.h>
#include <math.h>

#define OBS 8
#define SEQL 12
#define G 96
#define PP 16
#define B 1536
#define HD 128
#define ED 64
#define BOT 1024
#define MIDD 512
#define CTXD (HD + BOT)   /* 1152 */
#define MLPH 1024

typedef __attribute__((ext_vector_type(8))) short bf16x8;
typedef __attribute__((ext_vector_type(4))) float f32x4;

__device__ inline short f2bf(float x) {
    union { float f; unsigned u; } v; v.f = x;
    unsigned r = v.u + 0x7fffu + ((v.u >> 16) & 1u);   // RNE
    return (short)(r >> 16);
}

// ---------------------------------------------------------------------------
// setup kernels
// ---------------------------------------------------------------------------
// B-matrix -> MFMA-fragment-order bf16. src is (Nrows x Kcols) row-major fp32.
// dst unit u = (kt*NT + nt)*64 + lane: B[n=nt*16+(l&15)][k=kt*32+((l>>4)<<3)+e]
__global__ void swizzleB_kernel(const float* __restrict__ src, unsigned short* __restrict__ dst,
                                int NT, int K, int total) {
    int u = blockIdx.x * 256 + threadIdx.x;
    if (u >= total) return;
    int l = u & 63; int v = u >> 6; int nt = v % NT; int kt = v / NT;
    int n = nt * 16 + (l & 15);
    int k = kt * 32 + ((l >> 4) << 3);
    const float* s = src + n * K + k;
    float4 s0 = *(const float4*)s;
    float4 s1 = *(const float4*)(s + 4);
    bf16x8 o;
    o[0] = f2bf(s0.x); o[1] = f2bf(s0.y); o[2] = f2bf(s0.z); o[3] = f2bf(s0.w);
    o[4] = f2bf(s1.x); o[5] = f2bf(s1.y); o[6] = f2bf(s1.z); o[7] = f2bf(s1.w);
    *(bf16x8*)(dst + u * 8) = o;
}

// gates B = [W_ih | W_hh] (512 x 192) -> frag order (6 kt x 32 nt)
__global__ void swizzle_cat_kernel(const float* __restrict__ W_ih, const float* __restrict__ W_hh,
                                   unsigned short* __restrict__ dst) {
    int u = blockIdx.x * 256 + threadIdx.x;   // 6*32*64 = 12288 units
    if (u >= 6 * 32 * 64) return;
    int l = u & 63; int v = u >> 6; int nt = v & 31; int kt = v >> 5;
    int n = nt * 16 + (l & 15);
    int k0 = kt * 32 + ((l >> 4) << 3);
    bf16x8 o;
#pragma unroll
    for (int e = 0; e < 8; ++e) {
        int k = k0 + e;
        float val = (k < ED) ? W_ih[n * ED + k] : W_hh[n * HD + (k - ED)];
        o[e] = f2bf(val);
    }
    *(bf16x8*)(dst + u * 8) = o;
}

// Ab B-matrix = [Wp1_h | M0 | M1 | CV | 0pad] (512 x 160) -> frag order (5 kt x 32 nt)
__global__ void swizzle_p1_kernel(const float* __restrict__ Wp1, const float* __restrict__ M0,
                                  const float* __restrict__ M1, const float* __restrict__ CV,
                                  unsigned short* __restrict__ dst) {
    int u = blockIdx.x * 256 + threadIdx.x;   // 5*32*64 = 10240 units
    if (u >= 5 * 32 * 64) return;
    int l = u & 63; int v = u >> 6; int nt = v & 31; int kt = v >> 5;
    int n = nt * 16 + (l & 15);
    int k0 = kt * 32 + ((l >> 4) << 3);
    bf16x8 o;
#pragma unroll
    for (int e = 0; e < 8; ++e) {
        int k = k0 + e;
        float val;
        if (k < HD)       val = Wp1[n * (ED + HD) + ED + k];
        else if (k == HD)     val = M0[n];
        else if (k == HD + 1) val = M1[n];
        else if (k == HD + 2) val = CV[n];
        else                  val = 0.f;
        o[e] = f2bf(val);
    }
    *(bf16x8*)(dst + u * 8) = o;
}

// M = Wp1[:, :64] @ Wp_emb  (512x2), cvec = Wp1[:, :64] @ bp_emb + bp1
__global__ void mcvec_kernel(const float* __restrict__ Wp1, const float* __restrict__ Wp_emb,
                             const float* __restrict__ bp_emb, const float* __restrict__ bp1,
                             float* __restrict__ M0, float* __restrict__ M1, float* __restrict__ CV) {
    int r = blockIdx.x * blockDim.x + threadIdx.x;
    if (r >= MIDD) return;
    float m0 = 0.f, m1 = 0.f, cv = 0.f;
    for (int e = 0; e < ED; ++e) {
        float w = Wp1[r * (ED + HD) + e];
        m0 += w * Wp_emb[e * 2 + 0];
        m1 += w * Wp_emb[e * 2 + 1];
        cv += w * bp_emb[e];
    }
    M0[r] = m0; M1[r] = m1; CV[r] = cv + bp1[r];
}

__global__ void init_kernel(const float* __restrict__ obs_traj, const float* __restrict__ obs_traj_rel,
                            const float* __restrict__ h0, const float* __restrict__ c0,
                            const float* __restrict__ W_emb, const float* __restrict__ b_emb,
                            float* __restrict__ Hb, float* __restrict__ Cb,
                            float* __restrict__ POSb, float* __restrict__ DIN) {
    int b = blockIdx.x;
    int t = threadIdx.x; // 128
    Hb[b * HD + t] = h0[b * HD + t];
    Cb[b * HD + t] = c0[b * HD + t];
    if (t < 2) POSb[b * 2 + t] = obs_traj[((OBS - 1) * B + b) * 2 + t];
    if (t < ED) {
        float rx = obs_traj_rel[((OBS - 1) * B + b) * 2 + 0];
        float ry = obs_traj_rel[((OBS - 1) * B + b) * 2 + 1];
        DIN[b * ED + t] = W_emb[t * 2 + 0] * rx + W_emb[t * 2 + 1] * ry + b_emb[t];
    }
}

// ---------------------------------------------------------------------------
// fused step: gates MFMA -> LSTM cell (in-reg) -> rel_pos -> POS/DIN update ->
// Ab MFMA. Block = one scene (16 rows), 512 thr (8 waves).
// Wave w holds gates i,f,g,o for h-cols w*16..w*16+15 via nt = {w,8+w,16+w,24+w}.
// ---------------------------------------------------------------------------
__global__ __launch_bounds__(512) void step_kernel(
    const unsigned short* __restrict__ WcatF, const float* __restrict__ b_ih,
    const float* __restrict__ b_hh,
    const float* __restrict__ W_pos, const float* __restrict__ b_pos,
    const float* __restrict__ W_emb, const float* __restrict__ b_emb,
    const unsigned short* __restrict__ Wp1F2,
    float* __restrict__ Hb, float* __restrict__ Cb, float* __restrict__ POSb,
    float* __restrict__ DIN, unsigned short* __restrict__ Hbf,
    float* __restrict__ Ab, float* __restrict__ rel_out) {

    __shared__ unsigned short gf[6 * 64 * 8];    // gates A-frags, 6KB
    __shared__ unsigned short a2f[5 * 64 * 8];   // Ab A-frags, 5KB
    __shared__ float hsh[16 * HD];               // h_lstm, 8KB
    __shared__ float relsh[16][4];

    int gsc = blockIdx.x;          // scene
    int t = threadIdx.x;
    int lane = t & 63, w = t >> 6;
    int colid = lane & 15, quad = lane >> 4;

    // build gates A-frags: [din(64) | h_prev(128)], K=192 = 6 kt
    if (t < 384) {
        int kt = t >> 6;
        int j = lane & 15;
        int b = gsc * PP + j;
        int k0 = kt * 32 + ((lane >> 4) << 3);
        float4 x0, x1;
        if (k0 < ED) {
            const float4* p = (const float4*)(DIN + b * ED + k0);
            x0 = p[0]; x1 = p[1];
        } else {
            const float4* p = (const float4*)(Hb + b * HD + (k0 - ED));
            x0 = p[0]; x1 = p[1];
        }
        bf16x8 o;
        o[0] = f2bf(x0.x); o[1] = f2bf(x0.y); o[2] = f2bf(x0.z); o[3] = f2bf(x0.w);
        o[4] = f2bf(x1.x); o[5] = f2bf(x1.y); o[6] = f2bf(x1.z); o[7] = f2bf(x1.w);
        *(bf16x8*)(gf + t * 8) = o;
    }
    __syncthreads();

    // gates MFMA
    f32x4 acc[4];
#pragma unroll
    for (int gi = 0; gi < 4; ++gi) acc[gi] = (f32x4)0.f;
#pragma unroll
    for (int kt = 0; kt < 6; ++kt) {
        bf16x8 af = *(const bf16x8*)(gf + (kt * 64 + lane) * 8);
#pragma unroll
        for (int gi = 0; gi < 4; ++gi) {
            bf16x8 bfr = *(const bf16x8*)(WcatF + ((kt * 32 + gi * 8 + w) * 64 + lane) * 8);
            acc[gi] = __builtin_amdgcn_mfma_f32_16x16x32_bf16(af, bfr, acc[gi], 0, 0, 0);
        }
    }
    // LSTM cell, all four gates in-wave
    int hcol = w * 16 + colid;
    float bias[4];
#pragma unroll
    for (int gi = 0; gi < 4; ++gi) {
        int n = (gi * 8 + w) * 16 + colid;
        bias[gi] = b_ih[n] + b_hh[n];
    }
#pragma unroll
    for (int r = 0; r < 4; ++r) {
        int row = quad * 4 + r;
        int b = gsc * PP + row;
        float gI = acc[0][r] + bias[0];
        float gF = acc[1][r] + bias[1];
        float gG = acc[2][r] + bias[2];
        float gO = acc[3][r] + bias[3];
        float c = Cb[b * HD + hcol];
        float cn = (1.f / (1.f + expf(-gF))) * c + (1.f / (1.f + expf(-gI))) * tanhf(gG);
        float hn = (1.f / (1.f + expf(-gO))) * tanhf(cn);
        Cb[b * HD + hcol] = cn;
        Hbf[b * HD + hcol] = (unsigned short)f2bf(hn);
        hsh[row * HD + hcol] = hn;
    }
    __syncthreads();

    // rel_pos: 32 threads per row, shuffle reduce
    {
        int row = t >> 5, kk = t & 31;
        float r0 = 0.f, r1 = 0.f;
#pragma unroll
        for (int q = 0; q < 4; ++q) {
            int k = kk + q * 32;
            float hv = hsh[row * HD + k];
            r0 = fmaf(hv, W_pos[k], r0);
            r1 = fmaf(hv, W_pos[HD + k], r1);
        }
#pragma unroll
        for (int m = 16; m >= 1; m >>= 1) {
            r0 += __shfl_xor(r0, m, 64);
            r1 += __shfl_xor(r1, m, 64);
        }
        if (kk == 0) {
            int b = gsc * PP + row;
            r0 += b_pos[0]; r1 += b_pos[1];
            float px = POSb[b * 2 + 0] + r0;
            float py = POSb[b * 2 + 1] + r1;
            POSb[b * 2 + 0] = px; POSb[b * 2 + 1] = py;
            rel_out[b * 2 + 0] = r0; rel_out[b * 2 + 1] = r1;
            relsh[row][0] = r0; relsh[row][1] = r1; relsh[row][2] = px; relsh[row][3] = py;
        }
    }
    __syncthreads();

    // next dec_in
#pragma unroll
    for (int rep = 0; rep < 2; ++rep) {
        int idx = rep * 512 + t;
        int row = idx >> 6, e = idx & 63;
        int b = gsc * PP + row;
        DIN[b * ED + e] = W_emb[e * 2 + 0] * relsh[row][0] +
                          W_emb[e * 2 + 1] * relsh[row][1] + b_emb[e];
    }
    // Ab A-frags: [h(128) | px | py | 1 | 0pad], K=160 = 5 kt
    if (t < 320) {
        int kt = t >> 6;
        int j = lane & 15;
        int k0 = kt * 32 + ((lane >> 4) << 3);
        bf16x8 o;
#pragma unroll
        for (int e = 0; e < 8; ++e) {
            int k = k0 + e;
            float v;
            if (k < HD)            v = hsh[j * HD + k];
            else if (k == HD)      v = relsh[j][2];
            else if (k == HD + 1)  v = relsh[j][3];
            else if (k == HD + 2)  v = 1.f;
            else                   v = 0.f;
            o[e] = f2bf(v);
        }
        *(bf16x8*)(a2f + t * 8) = o;
    }
    __syncthreads();

    // Ab MFMA: wave w -> nt = w*4+q (512 cols total)
    f32x4 acc2[4];
#pragma unroll
    for (int q = 0; q < 4; ++q) acc2[q] = (f32x4)0.f;
#pragma unroll
    for (int kt = 0; kt < 5; ++kt) {
        bf16x8 af = *(const bf16x8*)(a2f + (kt * 64 + lane) * 8);
#pragma unroll
        for (int q = 0; q < 4; ++q) {
            bf16x8 bfr = *(const bf16x8*)(Wp1F2 + ((kt * 32 + w * 4 + q) * 64 + lane) * 8);
            acc2[q] = __builtin_amdgcn_mfma_f32_16x16x32_bf16(af, bfr, acc2[q], 0, 0, 0);
        }
    }
#pragma unroll
    for (int q = 0; q < 4; ++q)
#pragma unroll
        for (int r = 0; r < 4; ++r) {
            int b = gsc * PP + quad * 4 + r;
            Ab[b * MIDD + (w * 4 + q) * 16 + colid] = acc2[q][r];
        }
}

// ---------------------------------------------------------------------------
// pool v2: block = (scene g, igrp of 4 i), grid 384, 512 thr (8 waves).
// A-frags relu(a_j - s_i) built ONCE into LDS (bf16, frag order, 64KB),
// then wave w covers cols w*128..+127 for all 4 i. B streamed from L2.
// ---------------------------------------------------------------------------
__global__ __launch_bounds__(512) void pool_mfma2_kernel(
    const float* __restrict__ Ab, const float* __restrict__ POSb,
    const unsigned short* __restrict__ Wp2F, const float* __restrict__ bp2,
    const float* __restrict__ M0, const float* __restrict__ M1,
    unsigned short* __restrict__ POOLbf) {

    __shared__ float s_lds[4 * MIDD];                     // 8KB
    __shared__ unsigned short af_lds[4 * 16 * 64 * 8];    // 64KB

    int bi = blockIdx.x;
    int g = bi >> 2, igrp = bi & 3;
    int t = threadIdx.x, lane = t & 63, w = t >> 6;

    // s_i[k] for the 4 i's
#pragma unroll
    for (int rep = 0; rep < 4; ++rep) {
        int idx = rep * 512 + t;          // 2048
        int ii = idx >> 9, k = idx & 511;
        int i = g * PP + igrp * 4 + ii;
        s_lds[idx] = fmaf(M0[k], POSb[i * 2 + 0], M1[k] * POSb[i * 2 + 1]);
    }
    __syncthreads();
    // build A-frags once
#pragma unroll
    for (int rep = 0; rep < 8; ++rep) {
        int u = rep * 512 + t;            // 4096 units
        int ii = u >> 10, kt = (u >> 6) & 15, l = u & 63;
        int j = l & 15, k0 = kt * 32 + ((l >> 4) << 3);
        const float4* ap = (const float4*)(Ab + (g * PP + j) * MIDD + k0);
        float4 a0 = ap[0], a1 = ap[1];
        const float4* sp = (const float4*)(s_lds + ii * MIDD + k0);
        float4 s0 = sp[0], s1 = sp[1];
        bf16x8 o;
        o[0] = f2bf(fmaxf(a0.x - s0.x, 0.f));
        o[1] = f2bf(fmaxf(a0.y - s0.y, 0.f));
        o[2] = f2bf(fmaxf(a0.z - s0.z, 0.f));
        o[3] = f2bf(fmaxf(a0.w - s0.w, 0.f));
        o[4] = f2bf(fmaxf(a1.x - s1.x, 0.f));
        o[5] = f2bf(fmaxf(a1.y - s1.y, 0.f));
        o[6] = f2bf(fmaxf(a1.z - s1.z, 0.f));
        o[7] = f2bf(fmaxf(a1.w - s1.w, 0.f));
        *(bf16x8*)(af_lds + u * 8) = o;
    }
    __syncthreads();

    f32x4 acc[4][8];
#pragma unroll
    for (int ii = 0; ii < 4; ++ii)
#pragma unroll
        for (int n = 0; n < 8; ++n) acc[ii][n] = (f32x4)0.f;

    int ntb = w * 8;
    for (int kt = 0; kt < 16; ++kt) {
        bf16x8 bfr[8];
#pragma unroll
        for (int n = 0; n < 8; ++n)
            bfr[n] = *(const bf16x8*)(Wp2F + ((kt * 64 + ntb + n) * 64 + lane) * 8);
#pragma unroll
        for (int ii = 0; ii < 4; ++ii) {
            bf16x8 af = *(const bf16x8*)(af_lds + ((ii * 16 + kt) * 64 + lane) * 8);
#pragma unroll
            for (int n = 0; n < 8; ++n)
                acc[ii][n] = __builtin_amdgcn_mfma_f32_16x16x32_bf16(af, bfr[n], acc[ii][n], 0, 0, 0);
        }
    }

    int quad = lane >> 4, colid = lane & 15;
#pragma unroll
    for (int ii = 0; ii < 4; ++ii) {
        int i = igrp * 4 + ii;
#pragma unroll
        for (int n = 0; n < 8; ++n) {
            float m = fmaxf(fmaxf(acc[ii][n][0], acc[ii][n][1]),
                            fmaxf(acc[ii][n][2], acc[ii][n][3]));
            m = fmaxf(m, __shfl_xor(m, 16, 64));
            m = fmaxf(m, __shfl_xor(m, 32, 64));
            if (quad == 0) {
                int col = w * 128 + n * 16 + colid;
                float v = fmaxf(m + bp2[col], 0.f);
                POOLbf[(g * PP + i) * BOT + col] = (unsigned short)f2bf(v);
            }
        }
    }
}

// ---------------------------------------------------------------------------
// MLP1 (MFMA): [Hbf | POOLbf] (1536x1152) @ Wm1F -> relu -> Y1Mbf (1536x1024)
// ---------------------------------------------------------------------------
__global__ __launch_bounds__(256) void mlp1_mfma_kernel(
    const unsigned short* __restrict__ Hbf, const unsigned short* __restrict__ POOLbf,
    const unsigned short* __restrict__ Wm1F, const float* __restrict__ bm1,
    unsigned short* __restrict__ Y1Mbf) {

    __shared__ unsigned short a_f[16 * 64 * 8];   // 16KB
    int mg = blockIdx.x;       // 0..23
    int ng = blockIdx.y;       // 0..15
    int t = threadIdx.x, lane = t & 63, w = t >> 6;
    int rh = w >> 1, nh = w & 1;

    f32x4 acc[2][2];
#pragma unroll
    for (int a = 0; a < 2; ++a)
#pragma unroll
        for (int b = 0; b < 2; ++b) acc[a][b] = (f32x4)0.f;

    for (int c = 0; c < 9; ++c) {
        __syncthreads();
#pragma unroll
        for (int u0 = 0; u0 < 1024; u0 += 256) {
            int u = u0 + t;
            int rg = u >> 8, kt = (u >> 6) & 3, l = u & 63;
            int row = mg * 64 + rg * 16 + (l & 15);
            int kl = kt * 32 + ((l >> 4) << 3);
            const unsigned short* src = (c == 0) ? (Hbf + row * HD + kl)
                                                 : (POOLbf + row * BOT + (c - 1) * 128 + kl);
            *(bf16x8*)(a_f + u * 8) = *(const bf16x8*)src;
        }
        __syncthreads();
#pragma unroll
        for (int kt = 0; kt < 4; ++kt) {
            int ktg = c * 4 + kt;
            bf16x8 bfr[2];
#pragma unroll
            for (int j = 0; j < 2; ++j) {
                int ntg = ng * 4 + nh * 2 + j;
                bfr[j] = *(const bf16x8*)(Wm1F + ((ktg * 64 + ntg) * 64 + lane) * 8);
            }
#pragma unroll
            for (int ri = 0; ri < 2; ++ri) {
                int rg = rh * 2 + ri;
                bf16x8 af = *(const bf16x8*)(a_f + ((rg * 4 + kt) * 64 + lane) * 8);
#pragma unroll
                for (int j = 0; j < 2; ++j)
                    acc[ri][j] = __builtin_amdgcn_mfma_f32_16x16x32_bf16(af, bfr[j], acc[ri][j], 0, 0, 0);
            }
        }
    }
    int quad = lane >> 4, colid = lane & 15;
#pragma unroll
    for (int ri = 0; ri < 2; ++ri)
#pragma unroll
        for (int j = 0; j < 2; ++j) {
            int col = ng * 64 + (nh * 2 + j) * 16 + colid;
            float bb = bm1[col];
#pragma unroll
            for (int r = 0; r < 4; ++r) {
                int row = mg * 64 + (rh * 2 + ri) * 16 + quad * 4 + r;
                float v = fmaxf(acc[ri][j][r] + bb, 0.f);
                Y1Mbf[row * MLPH + col] = (unsigned short)f2bf(v);
            }
        }
}

// ---------------------------------------------------------------------------
// MLP2 (MFMA): Y1Mbf (1536x1024) @ Wm2F -> relu -> Hb fp32 (and h_out last step)
// ---------------------------------------------------------------------------
__global__ __launch_bounds__(256) void mlp2_mfma_kernel(
    const unsigned short* __restrict__ Y1Mbf, const unsigned short* __restrict__ Wm2F,
    const float* __restrict__ bm2, float* __restrict__ Hb, float* __restrict__ hout) {

    __shared__ unsigned short a_f[32 * 64 * 8];   // 32KB
    int rg = blockIdx.x;   // 0..95
    int t = threadIdx.x, lane = t & 63, w = t >> 6;

#pragma unroll
    for (int u0 = 0; u0 < 2048; u0 += 256) {
        int u = u0 + t;
        int kt = u >> 6, l = u & 63;
        int row = rg * 16 + (l & 15);
        int kl = kt * 32 + ((l >> 4) << 3);
        *(bf16x8*)(a_f + u * 8) = *(const bf16x8*)(Y1Mbf + row * MLPH + kl);
    }
    __syncthreads();

    f32x4 acc[2];
    acc[0] = (f32x4)0.f; acc[1] = (f32x4)0.f;
    for (int kt = 0; kt < 32; ++kt) {
        bf16x8 af = *(const bf16x8*)(a_f + (kt * 64 + lane) * 8);
#pragma unroll
        for (int j = 0; j < 2; ++j) {
            int ntg = w * 2 + j;
            bf16x8 bfr = *(const bf16x8*)(Wm2F + ((kt * 8 + ntg) * 64 + lane) * 8);
            acc[j] = __builtin_amdgcn_mfma_f32_16x16x32_bf16(af, bfr, acc[j], 0, 0, 0);
        }
    }
    int quad = lane >> 4, colid = lane & 15;
#pragma unroll
    for (int j = 0; j < 2; ++j) {
        int col = (w * 2 + j) * 16 + colid;
        float bb = bm2[col];
#pragma unroll
        for (int r = 0; r < 4; ++r) {
            int row = rg * 16 + quad * 4 + r;
            float v = fmaxf(acc[j][r] + bb, 0.f);
            Hb[row * HD + col] = v;
            if (hout) hout[row * HD + col] = v;
        }
    }
}

// ---------------------------------------------------------------------------
extern "C" void kernel_launch(void* const* d_in, const int* in_sizes, int n_in,
                              void* d_out, int out_size, void* d_ws, size_t ws_size,
                              hipStream_t stream) {
    const float* obs_traj     = (const float*)d_in[0];
    const float* obs_traj_rel = (const float*)d_in[1];
    const float* h0    = (const float*)d_in[3];
    const float* c0    = (const float*)d_in[4];
    const float* W_emb = (const float*)d_in[6];
    const float* b_emb = (const float*)d_in[7];
    const float* W_ih  = (const float*)d_in[8];
    const float* b_ih  = (const float*)d_in[9];
    const float* W_hh  = (const float*)d_in[10];
    const float* b_hh  = (const float*)d_in[11];
    const float* W_pos = (const float*)d_in[12];
    const float* b_pos = (const float*)d_in[13];
    const float* Wp_emb= (const float*)d_in[14];
    const float* bp_emb= (const float*)d_in[15];
    const float* Wp1   = (const float*)d_in[16];
    const float* bp1   = (const float*)d_in[17];
    const float* Wp2   = (const float*)d_in[18];
    const float* bp2   = (const float*)d_in[19];
    const float* Wm1   = (const float*)d_in[20];
    const float* bm1   = (const float*)d_in[21];
    const float* Wm2   = (const float*)d_in[22];
    const float* bm2   = (const float*)d_in[23];

    float* ws = (float*)d_ws;
    float* Hb    = ws; ws += B * HD;
    float* Cb    = ws; ws += B * HD;
    float* POSb  = ws; ws += B * 2;
    float* DIN   = ws; ws += B * ED;
    float* Ab    = ws; ws += B * MIDD;
    float* M0    = ws; ws += MIDD;
    float* M1    = ws; ws += MIDD;
    float* CV    = ws; ws += MIDD;
    unsigned short* us = (unsigned short*)ws;
    unsigned short* Hbf    = us; us += B * HD;
    unsigned short* POOLbf = us; us += B * BOT;
    unsigned short* Y1Mbf  = us; us += B * MLPH;
    unsigned short* WcatF  = us; us += 6 * 32 * 64 * 8;
    unsigned short* Wp1F2  = us; us += 5 * 32 * 64 * 8;
    unsigned short* Wp2F   = us; us += MIDD * BOT;
    unsigned short* Wm1F   = us; us += CTXD * MLPH;
    unsigned short* Wm2F   = us; us += MLPH * HD;

    float* out = (float*)d_out;
    float* rels_out = out;                 // (12,1536,2)
    float* h_out    = out + SEQL * B * 2;  // (1536,128)

    // setup
    {
        int tot = 16 * 64 * 64;   // Wp2: K=512, NT=64
        swizzleB_kernel<<<(tot + 255) / 256, 256, 0, stream>>>(Wp2, Wp2F, 64, MIDD, tot);
        tot = 36 * 64 * 64;       // Wm1: K=1152, NT=64
        swizzleB_kernel<<<(tot + 255) / 256, 256, 0, stream>>>(Wm1, Wm1F, 64, CTXD, tot);
        tot = 32 * 8 * 64;        // Wm2: K=1024, NT=8
        swizzleB_kernel<<<(tot + 255) / 256, 256, 0, stream>>>(Wm2, Wm2F, 8, MLPH, tot);
        swizzle_cat_kernel<<<(6 * 32 * 64 + 255) / 256, 256, 0, stream>>>(W_ih, W_hh, WcatF);
    }
    mcvec_kernel<<<2, 256, 0, stream>>>(Wp1, Wp_emb, bp_emb, bp1, M0, M1, CV);
    swizzle_p1_kernel<<<(5 * 32 * 64 + 255) / 256, 256, 0, stream>>>(Wp1, M0, M1, CV, Wp1F2);
    init_kernel<<<B, 128, 0, stream>>>(obs_traj, obs_traj_rel, h0, c0, W_emb, b_emb,
                                       Hb, Cb, POSb, DIN);

    for (int s = 0; s < SEQL; ++s) {
        step_kernel<<<G, 512, 0, stream>>>(
            WcatF, b_ih, b_hh, W_pos, b_pos, W_emb, b_emb, Wp1F2,
            Hb, Cb, POSb, DIN, Hbf, Ab, rels_out + s * B * 2);
        pool_mfma2_kernel<<<G * 4, 512, 0, stream>>>(Ab, POSb, Wp2F, bp2, M0, M1, POOLbf);
        mlp1_mfma_kernel<<<dim3(24, 16), 256, 0, stream>>>(Hbf, POOLbf, Wm1F, bm1, Y1Mbf);
        mlp2_mfma_kernel<<<G, 256, 0, stream>>>(Y1Mbf, Wm2F, bm2, Hb,
                                                (s == SEQL - 1) ? h_out : (float*)nullptr);
    }
}